// Round 3
// baseline (268.747 us; speedup 1.0000x reference)
//
#include <hip/hip_runtime.h>

typedef unsigned short ushort_t;
typedef __bf16 bf16x8 __attribute__((ext_vector_type(8)));
typedef ushort_t u16x8 __attribute__((ext_vector_type(8)));
typedef float f32x4 __attribute__((ext_vector_type(4)));

#define DEVI __device__ __forceinline__

// Problem dims
constexpr int Ed = 1024;   // embed
constexpr int Hh = 16;     // heads
constexpr int Dd = 64;     // head dim
constexpr int Ss = 2048;   // seq
constexpr int Mm = 4096;   // B*S rows

constexpr int NX4 = Mm * Ed / 4;
constexpr int NW4 = Ed * Ed / 4;

DEVI ushort_t f2bf(float f) {      // RNE (cold paths only)
    union { float f; unsigned int i; } v; v.f = f;
    unsigned int r = v.i + 0x7fffu + ((v.i >> 16) & 1u);
    return (ushort_t)(r >> 16);
}
DEVI ushort_t f2bf_hi(float f) {   // truncation: compiles to *_d16_hi store, 0 VALU
    union { float f; unsigned int i; } v; v.f = f;
    return (ushort_t)(v.i >> 16);
}
DEVI float fast_exp2(float x) {    // raw v_exp_f32 (no ocml wrapper)
    float r;
    asm("v_exp_f32 %0, %1" : "=v"(r) : "v"(x));
    return r;
}

// One-shot fp32 -> bf16 conversion of x + 4 weight matrices (RNE).
__global__ __launch_bounds__(256) void cvt_all(
    const float* __restrict__ x,  const float* __restrict__ Wq,
    const float* __restrict__ Wk, const float* __restrict__ Wv,
    const float* __restrict__ Wo,
    ushort_t* __restrict__ xb,  ushort_t* __restrict__ Wqb,
    ushort_t* __restrict__ Wkb, ushort_t* __restrict__ Wvb,
    ushort_t* __restrict__ Wob)
{
    int i = blockIdx.x * 256 + threadIdx.x;
    const float* s; ushort_t* d; int off;
    if (i < NX4)                { s = x;  d = xb;  off = i; }
    else if (i < NX4 + NW4)     { s = Wq; d = Wqb; off = i - NX4; }
    else if (i < NX4 + 2 * NW4) { s = Wk; d = Wkb; off = i - NX4 - NW4; }
    else if (i < NX4 + 3 * NW4) { s = Wv; d = Wvb; off = i - NX4 - 2 * NW4; }
    else                        { s = Wo; d = Wob; off = i - NX4 - 3 * NW4; }
    float4 v = ((const float4*)s)[off];
    ushort4 o; o.x = f2bf(v.x); o.y = f2bf(v.y); o.z = f2bf(v.z); o.w = f2bf(v.w);
    ((ushort4*)d)[off] = o;
}

// async global->LDS, 16B per lane
DEVI void gld16(const void* g, void* l) {
    __builtin_amdgcn_global_load_lds(
        (__attribute__((address_space(1))) void*)(g),
        (__attribute__((address_space(3))) void*)(l), 16, 0, 0);
}

// ---------------- NT GEMM core (m97 pattern + XOR-swizzled LDS) ------------
// LDS slot (row, g) holds source granule g^(row&7); fragment-read granule
// = (quad + 4*(ks/32)) ^ (l15&7) -> 2 lanes/bank = conflict-free (m136).
DEVI void gemm_core(const ushort_t* __restrict__ A, const ushort_t* __restrict__ W,
                    ushort_t* As, ushort_t* Bs, int tm, int tn, int K,
                    f32x4 acc[4][4])
{
    const int tid  = threadIdx.x;
    const int w    = tid >> 6;
    const int lane = tid & 63;
    const int quad = lane >> 4;
    const int l15  = lane & 15;
    const int wy   = w >> 1, wx = w & 1;
    const int rowc = lane >> 3;                      // row within 8-row chunk
    const int col8s = (((lane & 7) ^ rowc) * 8);     // swizzled source granule
    const int swq  = l15 & 7;                        // read-swizzle row term

    for (int k0 = 0; k0 < K; k0 += 64) {
        __syncthreads();
#pragma unroll
        for (int i = 0; i < 4; ++i) {
            int chunk = w * 4 + i;
            int row = chunk * 8 + rowc;              // row&7 == rowc
            gld16(A + (size_t)(tm + row) * K + k0 + col8s, (char*)As + chunk * 1024);
            gld16(W + (size_t)(tn + row) * K + k0 + col8s, (char*)Bs + chunk * 1024);
        }
        __syncthreads();
#pragma unroll
        for (int ks = 0; ks < 64; ks += 32) {
            const int k4 = ks >> 3;                  // 0 or 4
            bf16x8 a[4], b[4];
#pragma unroll
            for (int mi = 0; mi < 4; ++mi)
                a[mi] = *(const bf16x8*)&As[(wy * 64 + mi * 16 + l15) * 64
                                            + (((quad + k4) ^ swq) * 8)];
#pragma unroll
            for (int ni = 0; ni < 4; ++ni)
                b[ni] = *(const bf16x8*)&Bs[(wx * 64 + ni * 16 + l15) * 64
                                            + (((quad + k4) ^ swq) * 8)];
#pragma unroll
            for (int mi = 0; mi < 4; ++mi)
#pragma unroll
                for (int ni = 0; ni < 4; ++ni)
                    acc[mi][ni] = __builtin_amdgcn_mfma_f32_16x16x32_bf16(
                        a[mi], b[ni], acc[mi][ni], 0, 0, 0);
        }
    }
}

// Fused QKV projection. Q,K stored [B,H,S,D]; V stored [B,H,D,S].
__global__ __launch_bounds__(256, 3) void qkv_gemm(
    const ushort_t* __restrict__ x,
    const ushort_t* __restrict__ Wq, const float* __restrict__ bq,
    const ushort_t* __restrict__ Wk, const float* __restrict__ bk,
    const ushort_t* __restrict__ Wv, const float* __restrict__ bv,
    ushort_t* __restrict__ qo, ushort_t* __restrict__ ko, ushort_t* __restrict__ vto)
{
    __shared__ __align__(16) ushort_t As[128 * 64];
    __shared__ __align__(16) ushort_t Bs[128 * 64];
    const ushort_t* W; const float* bias; ushort_t* outp; int vmode;
    if (blockIdx.z == 0)      { W = Wq; bias = bq; outp = qo;  vmode = 0; }
    else if (blockIdx.z == 1) { W = Wk; bias = bk; outp = ko;  vmode = 0; }
    else                      { W = Wv; bias = bv; outp = vto; vmode = 1; }

    const int tm = blockIdx.x * 128, tn = blockIdx.y * 128;
    f32x4 acc[4][4] = {};
    gemm_core(x, W, As, Bs, tm, tn, Ed, acc);

    const int tid = threadIdx.x, w = tid >> 6, lane = tid & 63;
    const int quad = lane >> 4, l15 = lane & 15;
    const int wy = w >> 1, wx = w & 1;
#pragma unroll
    for (int ni = 0; ni < 4; ++ni) {
        int gc = tn + wx * 64 + ni * 16 + l15;
        float bb = bias[gc];
        int h = gc >> 6, d = gc & 63;
#pragma unroll
        for (int mi = 0; mi < 4; ++mi) {
#pragma unroll
            for (int r = 0; r < 4; ++r) {
                int gr = tm + wy * 64 + mi * 16 + quad * 4 + r;
                int b_ = gr >> 11, s_ = gr & 2047;
                float v = acc[mi][ni][r] + bb;
                size_t addr;
                if (vmode == 0) addr = ((size_t)(b_ * Hh + h) * Ss + s_) * Dd + d;
                else            addr = ((size_t)(b_ * Hh + h) * Dd + d) * Ss + s_;
                outp[addr] = f2bf_hi(v);
            }
        }
    }
}

// Output projection: out = ctx @ Wo^T + bo, [M,E] FP32. Penalty fused in block (0,0).
__global__ __launch_bounds__(256, 3) void out_gemm(
    const ushort_t* __restrict__ ctx, const ushort_t* __restrict__ Wo,
    const float* __restrict__ bo, const float* __restrict__ z,
    float* __restrict__ out)
{
    __shared__ __align__(16) ushort_t As[128 * 64];
    __shared__ __align__(16) ushort_t Bs[64 * 64];
    const int tm = blockIdx.x * 128, tn = blockIdx.y * 64;

    const int tid  = threadIdx.x;
    const int w    = tid >> 6;
    const int lane = tid & 63;
    const int quad = lane >> 4;
    const int l15  = lane & 15;
    const int wy   = w >> 1, wx = w & 1;
    const int rowc = lane >> 3;
    const int col8s = (((lane & 7) ^ rowc) * 8);
    const int swq  = l15 & 7;

    f32x4 acc[4][2] = {};
    for (int k0 = 0; k0 < Ed; k0 += 64) {
        __syncthreads();
#pragma unroll
        for (int i = 0; i < 4; ++i) {
            int chunk = w * 4 + i;
            int row = chunk * 8 + rowc;
            gld16(ctx + (size_t)(tm + row) * Ed + k0 + col8s, (char*)As + chunk * 1024);
        }
#pragma unroll
        for (int i = 0; i < 2; ++i) {
            int chunk = w * 2 + i;
            int row = chunk * 8 + rowc;
            gld16(Wo + (size_t)(tn + row) * Ed + k0 + col8s, (char*)Bs + chunk * 1024);
        }
        __syncthreads();
#pragma unroll
        for (int ks = 0; ks < 64; ks += 32) {
            const int k4 = ks >> 3;
            bf16x8 a[4], b[2];
#pragma unroll
            for (int mi = 0; mi < 4; ++mi)
                a[mi] = *(const bf16x8*)&As[(wy * 64 + mi * 16 + l15) * 64
                                            + (((quad + k4) ^ swq) * 8)];
#pragma unroll
            for (int ni = 0; ni < 2; ++ni)
                b[ni] = *(const bf16x8*)&Bs[(wx * 32 + ni * 16 + l15) * 64
                                            + (((quad + k4) ^ swq) * 8)];
#pragma unroll
            for (int mi = 0; mi < 4; ++mi)
#pragma unroll
                for (int ni = 0; ni < 2; ++ni)
                    acc[mi][ni] = __builtin_amdgcn_mfma_f32_16x16x32_bf16(
                        a[mi], b[ni], acc[mi][ni], 0, 0, 0);
        }
    }

#pragma unroll
    for (int ni = 0; ni < 2; ++ni) {
        int gc = tn + wx * 32 + ni * 16 + l15;
        float bb = bo[gc];
#pragma unroll
        for (int mi = 0; mi < 4; ++mi)
#pragma unroll
            for (int r = 0; r < 4; ++r) {
                int gr = tm + wy * 64 + mi * 16 + quad * 4 + r;
                out[(size_t)gr * Ed + gc] = acc[mi][ni][r] + bb;
            }
    }

    if (blockIdx.x == 0 && blockIdx.y == 0 && tid == 0) {
        float s = 0.f;
        for (int hh = 0; hh < Hh; ++hh) s += 1.f / (1.f + __expf(-z[hh]));
        out[(size_t)Mm * Ed] = s * 0.01f;
    }
}

// Flash attention v19: K dbuf in LDS (1 barrier/tile), V read DIRECT from
// global (Vt is [B,H,D,S] so each B-fragment is a contiguous 16B lane-load).
// XCD-aware block remap: linear id -> bh = (lin&7)*4 + ((lin>>3)&3),
// qt = lin>>5 (bijective). Round-robin dispatch then gives each XCD exactly
// 4 heads: K+V+Q working set = 3MB < 4MB per-XCD L2, so the direct-V (and
// K-DMA) reads are L2-hits instead of cross-XCD L3/HBM re-fetches.
// __launch_bounds__(256,3): <=170 VGPR so the 32-VGPR vf[] set can't spill;
// 3 blocks/CU = 12 waves/CU. grid = (S/64, B*H).
__global__ __launch_bounds__(256, 3) void attn(
    const ushort_t* __restrict__ Q, const ushort_t* __restrict__ Kk,
    const ushort_t* __restrict__ Vt, const float* __restrict__ z,
    ushort_t* __restrict__ ctx)
{
    __shared__ __align__(16) ushort_t Ks[2][64 * 64];  // swizzled [key][d], dbuf
    __shared__ __align__(16) ushort_t Ps[4][16 * 68];  // per-wave P scratch

    const int tid = threadIdx.x, w = tid >> 6, lane = tid & 63;
    const int quad = lane >> 4, l15 = lane & 15;
    const int lin = blockIdx.x + 32 * blockIdx.y;   // 0..1023
    const int qt = lin >> 5;                        // 0..31
    const int bh = (lin & 7) * 4 + ((lin >> 3) & 3);// 0..31, XCD-local heads
    const int h = bh & (Hh - 1), b_ = bh >> 4;
    const size_t base = (size_t)bh * Ss * Dd;

    const float gate = 1.f / (1.f + __expf(-z[h]));
    const float scl2 = gate * 0.125f * 1.44269504f;  // gate/sqrt(D) * log2(e)

    bf16x8 aQ[2];
#pragma unroll
    for (int c = 0; c < 2; ++c)
        aQ[c] = *(const bf16x8*)&Q[base + (size_t)(qt * 64 + w * 16 + l15) * Dd
                                   + c * 32 + quad * 8];

    const int rowA = w * 16 + (lane >> 3);
    const int rowB = rowA + 8;
    const int gsA  = (lane & 7) ^ (rowA & 7);
    const int gsB  = (lane & 7) ^ (rowB & 7);
    const ushort_t* kSrcA = Kk + base + (size_t)rowA * Dd + gsA * 8;
    const ushort_t* kSrcB = Kk + base + (size_t)rowB * Dd + gsB * 8;
    // direct-V: lane's row base (d = ni*16 + l15), key offset quad*8
    const ushort_t* vBase = Vt + base + (size_t)l15 * Ss + quad * 8;

    f32x4 accO[4] = {};
    float lsum[4] = {0.f, 0.f, 0.f, 0.f};

    const int swq = (l15 & 7) * 8;

    // prologue: stage K(0) into Ks[0]
    gld16(kSrcA, &Ks[0][(w * 2) * 512]);
    gld16(kSrcB, &Ks[0][(w * 2 + 1) * 512]);

    for (int kt = 0; kt < Ss / 64; ++kt) {
        const int cur = kt & 1, nxt = cur ^ 1;
        __syncthreads();   // K(kt) visible (own vmcnt drained at barrier);
                           // all waves done reading Ks[nxt] from tile kt-1

        // V(kt) fragments direct from global (L2-local after XCD remap).
        bf16x8 vf[2][4];
#pragma unroll
        for (int ni = 0; ni < 4; ++ni) {
            const ushort_t* vp = vBase + (size_t)(ni * 16) * Ss + kt * 64;
            vf[0][ni] = *(const bf16x8*)(vp);        // keys c=0: quad*8 .. +8
            vf[1][ni] = *(const bf16x8*)(vp + 32);   // keys c=1: 32+quad*8 .. +8
        }

        if (kt + 1 < Ss / 64) {   // prefetch K(kt+1) into Ks[nxt]
            gld16(kSrcA + (size_t)(kt + 1) * 64 * Dd, &Ks[nxt][(w * 2) * 512]);
            gld16(kSrcB + (size_t)(kt + 1) * 64 * Dd, &Ks[nxt][(w * 2 + 1) * 512]);
        }

        // S = Q K^T on Ks[cur]
        f32x4 sAcc[4] = {};
#pragma unroll
        for (int ni = 0; ni < 4; ++ni) {
            bf16x8 b0 = *(const bf16x8*)&Ks[cur][(ni * 16 + l15) * 64 + ((quad * 8) ^ swq)];
            bf16x8 b1 = *(const bf16x8*)&Ks[cur][(ni * 16 + l15) * 64 + (((quad + 4) * 8) ^ swq)];
            sAcc[ni] = __builtin_amdgcn_mfma_f32_16x16x32_bf16(aQ[0], b0, sAcc[ni], 0, 0, 0);
            sAcc[ni] = __builtin_amdgcn_mfma_f32_16x16x32_bf16(aQ[1], b1, sAcc[ni], 0, 0, 0);
        }

        // softmax (per-wave; P round-trips through Ps[w], lgkmcnt-ordered)
#pragma unroll
        for (int ni = 0; ni < 4; ++ni)
#pragma unroll
            for (int r = 0; r < 4; ++r) {
                float p = fast_exp2(sAcc[ni][r] * scl2);
                lsum[r] += p;
                Ps[w][(quad * 4 + r) * 68 + ni * 16 + l15] = f2bf_hi(p);
            }

        // O += P V   (V from registers; no barrier needed)
#pragma unroll
        for (int c = 0; c < 2; ++c) {
            bf16x8 aP = *(const bf16x8*)&Ps[w][l15 * 68 + c * 32 + quad * 8];
#pragma unroll
            for (int ni = 0; ni < 4; ++ni)
                accO[ni] = __builtin_amdgcn_mfma_f32_16x16x32_bf16(aP, vf[c][ni], accO[ni], 0, 0, 0);
        }
    }

#pragma unroll
    for (int r = 0; r < 4; ++r) {
        lsum[r] += __shfl_xor(lsum[r], 1);
        lsum[r] += __shfl_xor(lsum[r], 2);
        lsum[r] += __shfl_xor(lsum[r], 4);
        lsum[r] += __shfl_xor(lsum[r], 8);
    }

#pragma unroll
    for (int r = 0; r < 4; ++r) {
        int srow = qt * 64 + w * 16 + quad * 4 + r;
        float inv = 1.f / lsum[r];
#pragma unroll
        for (int ni = 0; ni < 4; ++ni) {
            int d = ni * 16 + l15;
            ctx[((size_t)(b_ * Ss + srow)) * Ed + h * Dd + d] = f2bf_hi(accO[ni][r] * inv);
        }
    }
}

extern "C" void kernel_launch(void* const* d_in, const int* in_sizes, int n_in,
                              void* d_out, int out_size, void* d_ws, size_t ws_size,
                              hipStream_t stream) {
    const float* x  = (const float*)d_in[0];
    const float* Wq = (const float*)d_in[1];
    const float* bq = (const float*)d_in[2];
    const float* Wk = (const float*)d_in[3];
    const float* bk = (const float*)d_in[4];
    const float* Wv = (const float*)d_in[5];
    const float* bv = (const float*)d_in[6];
    const float* Wo = (const float*)d_in[7];
    const float* bo = (const float*)d_in[8];
    const float* z  = (const float*)d_in[9];
    float* out = (float*)d_out;

    ushort_t* xb  = (ushort_t*)d_ws;              // [M,E]     8 MB
    ushort_t* Wqb = xb  + (size_t)Mm * Ed;        // [E,E]     2 MB
    ushort_t* Wkb = Wqb + (size_t)Ed * Ed;
    ushort_t* Wvb = Wkb + (size_t)Ed * Ed;
    ushort_t* Wob = Wvb + (size_t)Ed * Ed;
    ushort_t* qw  = Wob + (size_t)Ed * Ed;        // [B,H,S,D] 8 MB
    ushort_t* kw  = qw + (size_t)Mm * Ed;         // [B,H,S,D] 8 MB
    ushort_t* vT  = kw + (size_t)Mm * Ed;         // [B,H,D,S] 8 MB
    ushort_t* cx  = vT + (size_t)Mm * Ed;         // [B,S,E]   8 MB

    dim3 blk(256);
    cvt_all<<<dim3((NX4 + 4 * NW4) / 256), blk, 0, stream>>>(
        x, Wq, Wk, Wv, Wo, xb, Wqb, Wkb, Wvb, Wob);
    qkv_gemm<<<dim3(Mm / 128, Ed / 128, 3), blk, 0, stream>>>(
        xb, Wqb, bq, Wkb, bk, Wvb, bv, qw, kw, vT);
    attn<<<dim3(Ss / 64, 2 * Hh), blk, 0, stream>>>(qw, kw, vT, z, cx);
    out_gemm<<<dim3(Mm / 128, Ed / 64), blk, 0, stream>>>(cx, Wob, bo, z, out);
}

// Round 4
// 227.500 us; speedup vs baseline: 1.1813x; 1.1813x over previous
//
#include <hip/hip_runtime.h>

typedef unsigned short ushort_t;
typedef __bf16 bf16x8 __attribute__((ext_vector_type(8)));
typedef ushort_t u16x8 __attribute__((ext_vector_type(8)));
typedef float f32x4 __attribute__((ext_vector_type(4)));

#define DEVI __device__ __forceinline__

// Problem dims
constexpr int Ed = 1024;   // embed
constexpr int Hh = 16;     // heads
constexpr int Dd = 64;     // head dim
constexpr int Ss = 2048;   // seq
constexpr int Mm = 4096;   // B*S rows

constexpr int NX4 = Mm * Ed / 4;
constexpr int NW4 = Ed * Ed / 4;

DEVI ushort_t f2bf(float f) {      // RNE (cold paths only)
    union { float f; unsigned int i; } v; v.f = f;
    unsigned int r = v.i + 0x7fffu + ((v.i >> 16) & 1u);
    return (ushort_t)(r >> 16);
}
DEVI ushort_t f2bf_hi(float f) {   // truncation: compiles to *_d16_hi store, 0 VALU
    union { float f; unsigned int i; } v; v.f = f;
    return (ushort_t)(v.i >> 16);
}
DEVI float fast_exp2(float x) {    // raw v_exp_f32 (no ocml wrapper)
    float r;
    asm("v_exp_f32 %0, %1" : "=v"(r) : "v"(x));
    return r;
}

// One-shot fp32 -> bf16 conversion of x + 4 weight matrices (RNE).
__global__ __launch_bounds__(256) void cvt_all(
    const float* __restrict__ x,  const float* __restrict__ Wq,
    const float* __restrict__ Wk, const float* __restrict__ Wv,
    const float* __restrict__ Wo,
    ushort_t* __restrict__ xb,  ushort_t* __restrict__ Wqb,
    ushort_t* __restrict__ Wkb, ushort_t* __restrict__ Wvb,
    ushort_t* __restrict__ Wob)
{
    int i = blockIdx.x * 256 + threadIdx.x;
    const float* s; ushort_t* d; int off;
    if (i < NX4)                { s = x;  d = xb;  off = i; }
    else if (i < NX4 + NW4)     { s = Wq; d = Wqb; off = i - NX4; }
    else if (i < NX4 + 2 * NW4) { s = Wk; d = Wkb; off = i - NX4 - NW4; }
    else if (i < NX4 + 3 * NW4) { s = Wv; d = Wvb; off = i - NX4 - 2 * NW4; }
    else                        { s = Wo; d = Wob; off = i - NX4 - 3 * NW4; }
    float4 v = ((const float4*)s)[off];
    ushort4 o; o.x = f2bf(v.x); o.y = f2bf(v.y); o.z = f2bf(v.z); o.w = f2bf(v.w);
    ((ushort4*)d)[off] = o;
}

// async global->LDS, 16B per lane
DEVI void gld16(const void* g, void* l) {
    __builtin_amdgcn_global_load_lds(
        (__attribute__((address_space(1))) void*)(g),
        (__attribute__((address_space(3))) void*)(l), 16, 0, 0);
}

// ---------------- NT GEMM core (m97 pattern + XOR-swizzled LDS) ------------
// LDS slot (row, g) holds source granule g^(row&7); fragment-read granule
// = (quad + 4*(ks/32)) ^ (l15&7) -> 2 lanes/bank = conflict-free (m136).
DEVI void gemm_core(const ushort_t* __restrict__ A, const ushort_t* __restrict__ W,
                    ushort_t* As, ushort_t* Bs, int tm, int tn, int K,
                    f32x4 acc[4][4])
{
    const int tid  = threadIdx.x;
    const int w    = tid >> 6;
    const int lane = tid & 63;
    const int quad = lane >> 4;
    const int l15  = lane & 15;
    const int wy   = w >> 1, wx = w & 1;
    const int rowc = lane >> 3;                      // row within 8-row chunk
    const int col8s = (((lane & 7) ^ rowc) * 8);     // swizzled source granule
    const int swq  = l15 & 7;                        // read-swizzle row term

    for (int k0 = 0; k0 < K; k0 += 64) {
        __syncthreads();
#pragma unroll
        for (int i = 0; i < 4; ++i) {
            int chunk = w * 4 + i;
            int row = chunk * 8 + rowc;              // row&7 == rowc
            gld16(A + (size_t)(tm + row) * K + k0 + col8s, (char*)As + chunk * 1024);
            gld16(W + (size_t)(tn + row) * K + k0 + col8s, (char*)Bs + chunk * 1024);
        }
        __syncthreads();
#pragma unroll
        for (int ks = 0; ks < 64; ks += 32) {
            const int k4 = ks >> 3;                  // 0 or 4
            bf16x8 a[4], b[4];
#pragma unroll
            for (int mi = 0; mi < 4; ++mi)
                a[mi] = *(const bf16x8*)&As[(wy * 64 + mi * 16 + l15) * 64
                                            + (((quad + k4) ^ swq) * 8)];
#pragma unroll
            for (int ni = 0; ni < 4; ++ni)
                b[ni] = *(const bf16x8*)&Bs[(wx * 64 + ni * 16 + l15) * 64
                                            + (((quad + k4) ^ swq) * 8)];
#pragma unroll
            for (int mi = 0; mi < 4; ++mi)
#pragma unroll
                for (int ni = 0; ni < 4; ++ni)
                    acc[mi][ni] = __builtin_amdgcn_mfma_f32_16x16x32_bf16(
                        a[mi], b[ni], acc[mi][ni], 0, 0, 0);
        }
    }
}

// Fused QKV projection. Q,K stored [B,H,S,D]; V stored [B,H,D,S].
__global__ __launch_bounds__(256, 3) void qkv_gemm(
    const ushort_t* __restrict__ x,
    const ushort_t* __restrict__ Wq, const float* __restrict__ bq,
    const ushort_t* __restrict__ Wk, const float* __restrict__ bk,
    const ushort_t* __restrict__ Wv, const float* __restrict__ bv,
    ushort_t* __restrict__ qo, ushort_t* __restrict__ ko, ushort_t* __restrict__ vto)
{
    __shared__ __align__(16) ushort_t As[128 * 64];
    __shared__ __align__(16) ushort_t Bs[128 * 64];
    const ushort_t* W; const float* bias; ushort_t* outp; int vmode;
    if (blockIdx.z == 0)      { W = Wq; bias = bq; outp = qo;  vmode = 0; }
    else if (blockIdx.z == 1) { W = Wk; bias = bk; outp = ko;  vmode = 0; }
    else                      { W = Wv; bias = bv; outp = vto; vmode = 1; }

    const int tm = blockIdx.x * 128, tn = blockIdx.y * 128;
    f32x4 acc[4][4] = {};
    gemm_core(x, W, As, Bs, tm, tn, Ed, acc);

    const int tid = threadIdx.x, w = tid >> 6, lane = tid & 63;
    const int quad = lane >> 4, l15 = lane & 15;
    const int wy = w >> 1, wx = w & 1;
#pragma unroll
    for (int ni = 0; ni < 4; ++ni) {
        int gc = tn + wx * 64 + ni * 16 + l15;
        float bb = bias[gc];
        int h = gc >> 6, d = gc & 63;
#pragma unroll
        for (int mi = 0; mi < 4; ++mi) {
#pragma unroll
            for (int r = 0; r < 4; ++r) {
                int gr = tm + wy * 64 + mi * 16 + quad * 4 + r;
                int b_ = gr >> 11, s_ = gr & 2047;
                float v = acc[mi][ni][r] + bb;
                size_t addr;
                if (vmode == 0) addr = ((size_t)(b_ * Hh + h) * Ss + s_) * Dd + d;
                else            addr = ((size_t)(b_ * Hh + h) * Dd + d) * Ss + s_;
                outp[addr] = f2bf_hi(v);
            }
        }
    }
}

// Output projection: out = ctx @ Wo^T + bo, [M,E] FP32. Penalty fused in block (0,0).
__global__ __launch_bounds__(256, 3) void out_gemm(
    const ushort_t* __restrict__ ctx, const ushort_t* __restrict__ Wo,
    const float* __restrict__ bo, const float* __restrict__ z,
    float* __restrict__ out)
{
    __shared__ __align__(16) ushort_t As[128 * 64];
    __shared__ __align__(16) ushort_t Bs[64 * 64];
    const int tm = blockIdx.x * 128, tn = blockIdx.y * 64;

    const int tid  = threadIdx.x;
    const int w    = tid >> 6;
    const int lane = tid & 63;
    const int quad = lane >> 4;
    const int l15  = lane & 15;
    const int wy   = w >> 1, wx = w & 1;
    const int rowc = lane >> 3;
    const int col8s = (((lane & 7) ^ rowc) * 8);
    const int swq  = l15 & 7;

    f32x4 acc[4][2] = {};
    for (int k0 = 0; k0 < Ed; k0 += 64) {
        __syncthreads();
#pragma unroll
        for (int i = 0; i < 4; ++i) {
            int chunk = w * 4 + i;
            int row = chunk * 8 + rowc;
            gld16(ctx + (size_t)(tm + row) * Ed + k0 + col8s, (char*)As + chunk * 1024);
        }
#pragma unroll
        for (int i = 0; i < 2; ++i) {
            int chunk = w * 2 + i;
            int row = chunk * 8 + rowc;
            gld16(Wo + (size_t)(tn + row) * Ed + k0 + col8s, (char*)Bs + chunk * 1024);
        }
        __syncthreads();
#pragma unroll
        for (int ks = 0; ks < 64; ks += 32) {
            const int k4 = ks >> 3;
            bf16x8 a[4], b[2];
#pragma unroll
            for (int mi = 0; mi < 4; ++mi)
                a[mi] = *(const bf16x8*)&As[(wy * 64 + mi * 16 + l15) * 64
                                            + (((quad + k4) ^ swq) * 8)];
#pragma unroll
            for (int ni = 0; ni < 2; ++ni)
                b[ni] = *(const bf16x8*)&Bs[(wx * 32 + ni * 16 + l15) * 64
                                            + (((quad + k4) ^ swq) * 8)];
#pragma unroll
            for (int mi = 0; mi < 4; ++mi)
#pragma unroll
                for (int ni = 0; ni < 2; ++ni)
                    acc[mi][ni] = __builtin_amdgcn_mfma_f32_16x16x32_bf16(
                        a[mi], b[ni], acc[mi][ni], 0, 0, 0);
        }
    }

#pragma unroll
    for (int ni = 0; ni < 2; ++ni) {
        int gc = tn + wx * 32 + ni * 16 + l15;
        float bb = bo[gc];
#pragma unroll
        for (int mi = 0; mi < 4; ++mi)
#pragma unroll
            for (int r = 0; r < 4; ++r) {
                int gr = tm + wy * 64 + mi * 16 + quad * 4 + r;
                out[(size_t)gr * Ed + gc] = acc[mi][ni][r] + bb;
            }
    }

    if (blockIdx.x == 0 && blockIdx.y == 0 && tid == 0) {
        float s = 0.f;
        for (int hh = 0; hh < Hh; ++hh) s += 1.f / (1.f + __expf(-z[hh]));
        out[(size_t)Mm * Ed] = s * 0.01f;
    }
}

// Flash attention v20: v19 counters showed pure latency-bound (MfmaUtil 10%,
// VALU 15%, HBM 2%, 0 bank conflicts, VGPR=44 -> huge unused reg headroom).
// Fix: M_rep=2 -- each wave owns 32 q-rows (two 16-row fragments), block
// covers 128 q-rows, grid 1024->512 blocks. Per 64-key tile per wave:
// 32 MFMA (was 16) against the SAME stall budget (same 8 K ds_reads, same
// 8 direct-V global loads reused by both m, same 1 barrier, same K-DMA).
// K/V global re-reads halve. 2 blocks/CU; lost TLP covered by 2 independent
// per-wave chains. grid = (S/128, B*H).
__global__ __launch_bounds__(256, 2) void attn(
    const ushort_t* __restrict__ Q, const ushort_t* __restrict__ Kk,
    const ushort_t* __restrict__ Vt, const float* __restrict__ z,
    ushort_t* __restrict__ ctx)
{
    __shared__ __align__(16) ushort_t Ks[2][64 * 64];  // swizzled [key][d], dbuf
    __shared__ __align__(16) ushort_t Ps[4][32 * 68];  // per-wave P scratch (32 q-rows)

    const int tid = threadIdx.x, w = tid >> 6, lane = tid & 63;
    const int quad = lane >> 4, l15 = lane & 15;
    const int lin = blockIdx.x + 16 * blockIdx.y;   // 0..511 (gridDim.x = 16)
    const int qt = lin >> 5;                        // 0..15 (128-row q tile)
    const int bh = (lin & 7) * 4 + ((lin >> 3) & 3);// 0..31, XCD-local heads
    const int h = bh & (Hh - 1), b_ = bh >> 4;
    const size_t base = (size_t)bh * Ss * Dd;

    const float gate = 1.f / (1.f + __expf(-z[h]));
    const float scl2 = gate * 0.125f * 1.44269504f;  // gate/sqrt(D) * log2(e)

    bf16x8 aQ[2][2];
#pragma unroll
    for (int m = 0; m < 2; ++m)
#pragma unroll
        for (int c = 0; c < 2; ++c)
            aQ[m][c] = *(const bf16x8*)&Q[base
                + (size_t)(qt * 128 + w * 32 + m * 16 + l15) * Dd + c * 32 + quad * 8];

    const int rowA = w * 16 + (lane >> 3);
    const int rowB = rowA + 8;
    const int gsA  = (lane & 7) ^ (rowA & 7);
    const int gsB  = (lane & 7) ^ (rowB & 7);
    const ushort_t* kSrcA = Kk + base + (size_t)rowA * Dd + gsA * 8;
    const ushort_t* kSrcB = Kk + base + (size_t)rowB * Dd + gsB * 8;
    // direct-V: lane's row base (d = ni*16 + l15), key offset quad*8
    const ushort_t* vBase = Vt + base + (size_t)l15 * Ss + quad * 8;

    f32x4 accO[2][4] = {};
    float lsum[2][4] = {};

    const int swq = (l15 & 7) * 8;

    // prologue: stage K(0) into Ks[0]
    gld16(kSrcA, &Ks[0][(w * 2) * 512]);
    gld16(kSrcB, &Ks[0][(w * 2 + 1) * 512]);

    for (int kt = 0; kt < Ss / 64; ++kt) {
        const int cur = kt & 1, nxt = cur ^ 1;
        __syncthreads();   // K(kt) visible; all waves done with Ks[nxt] of kt-1

        // V(kt) fragments direct from global (L2-local after XCD remap),
        // reused by both m fragments.
        bf16x8 vf[2][4];
#pragma unroll
        for (int ni = 0; ni < 4; ++ni) {
            const ushort_t* vp = vBase + (size_t)(ni * 16) * Ss + kt * 64;
            vf[0][ni] = *(const bf16x8*)(vp);        // keys c=0: quad*8 .. +8
            vf[1][ni] = *(const bf16x8*)(vp + 32);   // keys c=1: 32+quad*8 .. +8
        }

        if (kt + 1 < Ss / 64) {   // prefetch K(kt+1) into Ks[nxt]
            gld16(kSrcA + (size_t)(kt + 1) * 64 * Dd, &Ks[nxt][(w * 2) * 512]);
            gld16(kSrcB + (size_t)(kt + 1) * 64 * Dd, &Ks[nxt][(w * 2 + 1) * 512]);
        }

        // S = Q K^T on Ks[cur]; K fragments shared across both m chains
        f32x4 sAcc[2][4] = {};
#pragma unroll
        for (int ni = 0; ni < 4; ++ni) {
            bf16x8 b0 = *(const bf16x8*)&Ks[cur][(ni * 16 + l15) * 64 + ((quad * 8) ^ swq)];
            bf16x8 b1 = *(const bf16x8*)&Ks[cur][(ni * 16 + l15) * 64 + (((quad + 4) * 8) ^ swq)];
#pragma unroll
            for (int m = 0; m < 2; ++m) {
                sAcc[m][ni] = __builtin_amdgcn_mfma_f32_16x16x32_bf16(aQ[m][0], b0, sAcc[m][ni], 0, 0, 0);
                sAcc[m][ni] = __builtin_amdgcn_mfma_f32_16x16x32_bf16(aQ[m][1], b1, sAcc[m][ni], 0, 0, 0);
            }
        }

        // softmax (per-wave; P round-trips through Ps[w], lgkmcnt-ordered)
#pragma unroll
        for (int m = 0; m < 2; ++m)
#pragma unroll
            for (int ni = 0; ni < 4; ++ni)
#pragma unroll
                for (int r = 0; r < 4; ++r) {
                    float p = fast_exp2(sAcc[m][ni][r] * scl2);
                    lsum[m][r] += p;
                    Ps[w][(m * 16 + quad * 4 + r) * 68 + ni * 16 + l15] = f2bf_hi(p);
                }

        // O += P V   (V in registers, shared across m; no barrier needed)
#pragma unroll
        for (int c = 0; c < 2; ++c) {
            bf16x8 aP0 = *(const bf16x8*)&Ps[w][l15 * 68 + c * 32 + quad * 8];
            bf16x8 aP1 = *(const bf16x8*)&Ps[w][(16 + l15) * 68 + c * 32 + quad * 8];
#pragma unroll
            for (int ni = 0; ni < 4; ++ni) {
                accO[0][ni] = __builtin_amdgcn_mfma_f32_16x16x32_bf16(aP0, vf[c][ni], accO[0][ni], 0, 0, 0);
                accO[1][ni] = __builtin_amdgcn_mfma_f32_16x16x32_bf16(aP1, vf[c][ni], accO[1][ni], 0, 0, 0);
            }
        }
    }

#pragma unroll
    for (int m = 0; m < 2; ++m)
#pragma unroll
        for (int r = 0; r < 4; ++r) {
            lsum[m][r] += __shfl_xor(lsum[m][r], 1);
            lsum[m][r] += __shfl_xor(lsum[m][r], 2);
            lsum[m][r] += __shfl_xor(lsum[m][r], 4);
            lsum[m][r] += __shfl_xor(lsum[m][r], 8);
        }

#pragma unroll
    for (int m = 0; m < 2; ++m)
#pragma unroll
        for (int r = 0; r < 4; ++r) {
            int srow = qt * 128 + w * 32 + m * 16 + quad * 4 + r;
            float inv = 1.f / lsum[m][r];
#pragma unroll
            for (int ni = 0; ni < 4; ++ni) {
                int d = ni * 16 + l15;
                ctx[((size_t)(b_ * Ss + srow)) * Ed + h * Dd + d] = f2bf_hi(accO[m][ni][r] * inv);
            }
        }
}

extern "C" void kernel_launch(void* const* d_in, const int* in_sizes, int n_in,
                              void* d_out, int out_size, void* d_ws, size_t ws_size,
                              hipStream_t stream) {
    const float* x  = (const float*)d_in[0];
    const float* Wq = (const float*)d_in[1];
    const float* bq = (const float*)d_in[2];
    const float* Wk = (const float*)d_in[3];
    const float* bk = (const float*)d_in[4];
    const float* Wv = (const float*)d_in[5];
    const float* bv = (const float*)d_in[6];
    const float* Wo = (const float*)d_in[7];
    const float* bo = (const float*)d_in[8];
    const float* z  = (const float*)d_in[9];
    float* out = (float*)d_out;

    ushort_t* xb  = (ushort_t*)d_ws;              // [M,E]     8 MB
    ushort_t* Wqb = xb  + (size_t)Mm * Ed;        // [E,E]     2 MB
    ushort_t* Wkb = Wqb + (size_t)Ed * Ed;
    ushort_t* Wvb = Wkb + (size_t)Ed * Ed;
    ushort_t* Wob = Wvb + (size_t)Ed * Ed;
    ushort_t* qw  = Wob + (size_t)Ed * Ed;        // [B,H,S,D] 8 MB
    ushort_t* kw  = qw + (size_t)Mm * Ed;         // [B,H,S,D] 8 MB
    ushort_t* vT  = kw + (size_t)Mm * Ed;         // [B,H,D,S] 8 MB
    ushort_t* cx  = vT + (size_t)Mm * Ed;         // [B,S,E]   8 MB

    dim3 blk(256);
    cvt_all<<<dim3((NX4 + 4 * NW4) / 256), blk, 0, stream>>>(
        x, Wq, Wk, Wv, Wo, xb, Wqb, Wkb, Wvb, Wob);
    qkv_gemm<<<dim3(Mm / 128, Ed / 128, 3), blk, 0, stream>>>(
        xb, Wqb, bq, Wkb, bk, Wvb, bv, qw, kw, vT);
    attn<<<dim3(Ss / 128, 2 * Hh), blk, 0, stream>>>(qw, kw, vT, z, cx);
    out_gemm<<<dim3(Mm / 128, Ed / 64), blk, 0, stream>>>(cx, Wob, bo, z, out);
}

// Round 5
// 209.558 us; speedup vs baseline: 1.2824x; 1.0856x over previous
//
#include <hip/hip_runtime.h>

typedef unsigned short ushort_t;
typedef __bf16 bf16x8 __attribute__((ext_vector_type(8)));
typedef ushort_t u16x8 __attribute__((ext_vector_type(8)));
typedef float f32x4 __attribute__((ext_vector_type(4)));
typedef unsigned int u32x2 __attribute__((ext_vector_type(2)));

#define DEVI __device__ __forceinline__

// Problem dims
constexpr int Ed = 1024;   // embed
constexpr int Hh = 16;     // heads
constexpr int Dd = 64;     // head dim
constexpr int Ss = 2048;   // seq
constexpr int Mm = 4096;   // B*S rows

constexpr int NX4 = Mm * Ed / 4;
constexpr int NW4 = Ed * Ed / 4;

DEVI ushort_t f2bf(float f) {      // RNE (cold paths only)
    union { float f; unsigned int i; } v; v.f = f;
    unsigned int r = v.i + 0x7fffu + ((v.i >> 16) & 1u);
    return (ushort_t)(r >> 16);
}
DEVI ushort_t f2bf_hi(float f) {   // truncation: compiles to *_d16_hi store, 0 VALU
    union { float f; unsigned int i; } v; v.f = f;
    return (ushort_t)(v.i >> 16);
}
DEVI unsigned int fbits(float f) {
    union { float f; unsigned int i; } v; v.f = f;
    return v.i;
}
DEVI float fast_exp2(float x) {    // raw v_exp_f32 (no ocml wrapper)
    float r;
    asm("v_exp_f32 %0, %1" : "=v"(r) : "v"(x));
    return r;
}

// One-shot fp32 -> bf16 conversion of x + 4 weight matrices (RNE).
__global__ __launch_bounds__(256) void cvt_all(
    const float* __restrict__ x,  const float* __restrict__ Wq,
    const float* __restrict__ Wk, const float* __restrict__ Wv,
    const float* __restrict__ Wo,
    ushort_t* __restrict__ xb,  ushort_t* __restrict__ Wqb,
    ushort_t* __restrict__ Wkb, ushort_t* __restrict__ Wvb,
    ushort_t* __restrict__ Wob)
{
    int i = blockIdx.x * 256 + threadIdx.x;
    const float* s; ushort_t* d; int off;
    if (i < NX4)                { s = x;  d = xb;  off = i; }
    else if (i < NX4 + NW4)     { s = Wq; d = Wqb; off = i - NX4; }
    else if (i < NX4 + 2 * NW4) { s = Wk; d = Wkb; off = i - NX4 - NW4; }
    else if (i < NX4 + 3 * NW4) { s = Wv; d = Wvb; off = i - NX4 - 2 * NW4; }
    else                        { s = Wo; d = Wob; off = i - NX4 - 3 * NW4; }
    float4 v = ((const float4*)s)[off];
    ushort4 o; o.x = f2bf(v.x); o.y = f2bf(v.y); o.z = f2bf(v.z); o.w = f2bf(v.w);
    ((ushort4*)d)[off] = o;
}

// async global->LDS, 16B per lane
DEVI void gld16(const void* g, void* l) {
    __builtin_amdgcn_global_load_lds(
        (__attribute__((address_space(1))) void*)(g),
        (__attribute__((address_space(3))) void*)(l), 16, 0, 0);
}

// ---------------- NT GEMM core (m97 pattern + XOR-swizzled LDS) ------------
// LDS slot (row, g) holds source granule g^(row&7); fragment-read granule
// = (quad + 4*(ks/32)) ^ (l15&7) -> 2 lanes/bank = conflict-free (m136).
DEVI void gemm_core(const ushort_t* __restrict__ A, const ushort_t* __restrict__ W,
                    ushort_t* As, ushort_t* Bs, int tm, int tn, int K,
                    f32x4 acc[4][4])
{
    const int tid  = threadIdx.x;
    const int w    = tid >> 6;
    const int lane = tid & 63;
    const int quad = lane >> 4;
    const int l15  = lane & 15;
    const int wy   = w >> 1, wx = w & 1;
    const int rowc = lane >> 3;                      // row within 8-row chunk
    const int col8s = (((lane & 7) ^ rowc) * 8);     // swizzled source granule
    const int swq  = l15 & 7;                        // read-swizzle row term

    for (int k0 = 0; k0 < K; k0 += 64) {
        __syncthreads();
#pragma unroll
        for (int i = 0; i < 4; ++i) {
            int chunk = w * 4 + i;
            int row = chunk * 8 + rowc;              // row&7 == rowc
            gld16(A + (size_t)(tm + row) * K + k0 + col8s, (char*)As + chunk * 1024);
            gld16(W + (size_t)(tn + row) * K + k0 + col8s, (char*)Bs + chunk * 1024);
        }
        __syncthreads();
#pragma unroll
        for (int ks = 0; ks < 64; ks += 32) {
            const int k4 = ks >> 3;                  // 0 or 4
            bf16x8 a[4], b[4];
#pragma unroll
            for (int mi = 0; mi < 4; ++mi)
                a[mi] = *(const bf16x8*)&As[(wy * 64 + mi * 16 + l15) * 64
                                            + (((quad + k4) ^ swq) * 8)];
#pragma unroll
            for (int ni = 0; ni < 4; ++ni)
                b[ni] = *(const bf16x8*)&Bs[(wx * 64 + ni * 16 + l15) * 64
                                            + (((quad + k4) ^ swq) * 8)];
#pragma unroll
            for (int mi = 0; mi < 4; ++mi)
#pragma unroll
                for (int ni = 0; ni < 4; ++ni)
                    acc[mi][ni] = __builtin_amdgcn_mfma_f32_16x16x32_bf16(
                        a[mi], b[ni], acc[mi][ni], 0, 0, 0);
        }
    }
}

// Fused QKV projection. Q,K stored [B,H,S,D]; V stored [B,H,D,S].
// V store packed: r=0..3 are 4 consecutive s at one d -> one 8B store
// (truncation pack == f2bf_hi numerics), vs 2B scatter at 4KB stride.
__global__ __launch_bounds__(256, 3) void qkv_gemm(
    const ushort_t* __restrict__ x,
    const ushort_t* __restrict__ Wq, const float* __restrict__ bq,
    const ushort_t* __restrict__ Wk, const float* __restrict__ bk,
    const ushort_t* __restrict__ Wv, const float* __restrict__ bv,
    ushort_t* __restrict__ qo, ushort_t* __restrict__ ko, ushort_t* __restrict__ vto)
{
    __shared__ __align__(16) ushort_t As[128 * 64];
    __shared__ __align__(16) ushort_t Bs[128 * 64];
    const ushort_t* W; const float* bias; ushort_t* outp; int vmode;
    if (blockIdx.z == 0)      { W = Wq; bias = bq; outp = qo;  vmode = 0; }
    else if (blockIdx.z == 1) { W = Wk; bias = bk; outp = ko;  vmode = 0; }
    else                      { W = Wv; bias = bv; outp = vto; vmode = 1; }

    const int tm = blockIdx.x * 128, tn = blockIdx.y * 128;
    f32x4 acc[4][4] = {};
    gemm_core(x, W, As, Bs, tm, tn, Ed, acc);

    const int tid = threadIdx.x, w = tid >> 6, lane = tid & 63;
    const int quad = lane >> 4, l15 = lane & 15;
    const int wy = w >> 1, wx = w & 1;
    if (vmode == 0) {
#pragma unroll
        for (int ni = 0; ni < 4; ++ni) {
            int gc = tn + wx * 64 + ni * 16 + l15;
            float bb = bias[gc];
            int h = gc >> 6, d = gc & 63;
#pragma unroll
            for (int mi = 0; mi < 4; ++mi) {
#pragma unroll
                for (int r = 0; r < 4; ++r) {
                    int gr = tm + wy * 64 + mi * 16 + quad * 4 + r;
                    int b_ = gr >> 11, s_ = gr & 2047;
                    float v = acc[mi][ni][r] + bb;
                    outp[((size_t)(b_ * Hh + h) * Ss + s_) * Dd + d] = f2bf_hi(v);
                }
            }
        }
    } else {
#pragma unroll
        for (int ni = 0; ni < 4; ++ni) {
            int gc = tn + wx * 64 + ni * 16 + l15;
            float bb = bias[gc];
            int h = gc >> 6, d = gc & 63;
#pragma unroll
            for (int mi = 0; mi < 4; ++mi) {
                int gr0 = tm + wy * 64 + mi * 16 + quad * 4;   // r=0; same batch for r=0..3
                int b_ = gr0 >> 11, s0 = gr0 & 2047;
                unsigned int u0 = fbits(acc[mi][ni][0] + bb);
                unsigned int u1 = fbits(acc[mi][ni][1] + bb);
                unsigned int u2 = fbits(acc[mi][ni][2] + bb);
                unsigned int u3 = fbits(acc[mi][ni][3] + bb);
                u32x2 pk;
                pk[0] = (u1 & 0xffff0000u) | (u0 >> 16);       // bf16[s0+1]:bf16[s0]
                pk[1] = (u3 & 0xffff0000u) | (u2 >> 16);       // bf16[s0+3]:bf16[s0+2]
                *(u32x2*)&outp[((size_t)(b_ * Hh + h) * Dd + d) * Ss + s0] = pk;
            }
        }
    }
}

// Output projection: out = ctx @ Wo^T + bo, [M,E] FP32. Penalty fused in block (0,0).
__global__ __launch_bounds__(256, 3) void out_gemm(
    const ushort_t* __restrict__ ctx, const ushort_t* __restrict__ Wo,
    const float* __restrict__ bo, const float* __restrict__ z,
    float* __restrict__ out)
{
    __shared__ __align__(16) ushort_t As[128 * 64];
    __shared__ __align__(16) ushort_t Bs[64 * 64];
    const int tm = blockIdx.x * 128, tn = blockIdx.y * 64;

    const int tid  = threadIdx.x;
    const int w    = tid >> 6;
    const int lane = tid & 63;
    const int quad = lane >> 4;
    const int l15  = lane & 15;
    const int wy   = w >> 1, wx = w & 1;
    const int rowc = lane >> 3;
    const int col8s = (((lane & 7) ^ rowc) * 8);
    const int swq  = l15 & 7;

    f32x4 acc[4][2] = {};
    for (int k0 = 0; k0 < Ed; k0 += 64) {
        __syncthreads();
#pragma unroll
        for (int i = 0; i < 4; ++i) {
            int chunk = w * 4 + i;
            int row = chunk * 8 + rowc;
            gld16(ctx + (size_t)(tm + row) * Ed + k0 + col8s, (char*)As + chunk * 1024);
        }
#pragma unroll
        for (int i = 0; i < 2; ++i) {
            int chunk = w * 2 + i;
            int row = chunk * 8 + rowc;
            gld16(Wo + (size_t)(tn + row) * Ed + k0 + col8s, (char*)Bs + chunk * 1024);
        }
        __syncthreads();
#pragma unroll
        for (int ks = 0; ks < 64; ks += 32) {
            const int k4 = ks >> 3;
            bf16x8 a[4], b[2];
#pragma unroll
            for (int mi = 0; mi < 4; ++mi)
                a[mi] = *(const bf16x8*)&As[(wy * 64 + mi * 16 + l15) * 64
                                            + (((quad + k4) ^ swq) * 8)];
#pragma unroll
            for (int ni = 0; ni < 2; ++ni)
                b[ni] = *(const bf16x8*)&Bs[(wx * 32 + ni * 16 + l15) * 64
                                            + (((quad + k4) ^ swq) * 8)];
#pragma unroll
            for (int mi = 0; mi < 4; ++mi)
#pragma unroll
                for (int ni = 0; ni < 2; ++ni)
                    acc[mi][ni] = __builtin_amdgcn_mfma_f32_16x16x32_bf16(
                        a[mi], b[ni], acc[mi][ni], 0, 0, 0);
        }
    }

#pragma unroll
    for (int ni = 0; ni < 2; ++ni) {
        int gc = tn + wx * 32 + ni * 16 + l15;
        float bb = bo[gc];
#pragma unroll
        for (int mi = 0; mi < 4; ++mi)
#pragma unroll
            for (int r = 0; r < 4; ++r) {
                int gr = tm + wy * 64 + mi * 16 + quad * 4 + r;
                out[(size_t)gr * Ed + gc] = acc[mi][ni][r] + bb;
            }
    }

    if (blockIdx.x == 0 && blockIdx.y == 0 && tid == 0) {
        float s = 0.f;
        for (int hh = 0; hh < Hh; ++hh) s += 1.f / (1.f + __expf(-z[hh]));
        out[(size_t)Mm * Ed] = s * 0.01f;
    }
}

// Flash attention v21: v20 + KVBLK=128 (two 64-key subtiles per barrier ->
// barriers 32->16; subtile-1 K ds_reads / V loads overlap subtile-0
// softmax+PV within one barrier interval) + s_setprio(1) around MFMA
// clusters (T5, proven +4-7% attn). Ps reuse across subtiles is safe:
// DS pipe is per-wave in-order (read-before-overwrite preserved).
// grid = (S/128, B*H) = 512 blocks, 2/CU. LDS 49.4KB.
__global__ __launch_bounds__(256, 2) void attn(
    const ushort_t* __restrict__ Q, const ushort_t* __restrict__ Kk,
    const ushort_t* __restrict__ Vt, const float* __restrict__ z,
    ushort_t* __restrict__ ctx)
{
    __shared__ __align__(16) ushort_t Ks[2][128 * 64];  // swizzled [key][d], dbuf 32KB
    __shared__ __align__(16) ushort_t Ps[4][32 * 68];   // per-wave P scratch (32 q-rows)

    const int tid = threadIdx.x, w = tid >> 6, lane = tid & 63;
    const int quad = lane >> 4, l15 = lane & 15;
    const int lin = blockIdx.x + 16 * blockIdx.y;   // 0..511 (gridDim.x = 16)
    const int qt = lin >> 5;                        // 0..15 (128-row q tile)
    const int bh = (lin & 7) * 4 + ((lin >> 3) & 3);// 0..31, XCD-local heads
    const int h = bh & (Hh - 1), b_ = bh >> 4;
    const size_t base = (size_t)bh * Ss * Dd;

    const float gate = 1.f / (1.f + __expf(-z[h]));
    const float scl2 = gate * 0.125f * 1.44269504f;  // gate/sqrt(D) * log2(e)

    bf16x8 aQ[2][2];
#pragma unroll
    for (int m = 0; m < 2; ++m)
#pragma unroll
        for (int c = 0; c < 2; ++c)
            aQ[m][c] = *(const bf16x8*)&Q[base
                + (size_t)(qt * 128 + w * 32 + m * 16 + l15) * Dd + c * 32 + quad * 8];

    // K staging: wave w owns rows w*32 .. w*32+31 (4 chunks of 8 rows)
    const int rowc = lane >> 3;                     // 0..7
    const int gs   = ((lane & 7) ^ rowc) * 8;       // swizzled source granule
    const ushort_t* kSrc[4];
#pragma unroll
    for (int i = 0; i < 4; ++i)
        kSrc[i] = Kk + base + (size_t)(w * 32 + i * 8 + rowc) * Dd + gs;
    // direct-V: lane's row base (d = ni*16 + l15), key offset quad*8
    const ushort_t* vBase = Vt + base + (size_t)l15 * Ss + quad * 8;

    f32x4 accO[2][4] = {};
    float lsum[2][4] = {};

    const int swq = (l15 & 7) * 8;

    // prologue: stage K-tile 0 (128 keys) into Ks[0]
#pragma unroll
    for (int i = 0; i < 4; ++i)
        gld16(kSrc[i], (char*)Ks[0] + (w * 4 + i) * 1024);

    for (int kt = 0; kt < Ss / 128; ++kt) {
        const int cur = kt & 1, nxt = cur ^ 1;
        __syncthreads();   // K(kt) visible; all waves done with Ks[nxt] of kt-1

        if (kt + 1 < Ss / 128) {   // prefetch K(kt+1) into Ks[nxt]
#pragma unroll
            for (int i = 0; i < 4; ++i)
                gld16(kSrc[i] + (size_t)(kt + 1) * 128 * Dd,
                      (char*)Ks[nxt] + (w * 4 + i) * 1024);
        }

#pragma unroll
        for (int sub = 0; sub < 2; ++sub) {
            // V fragments direct from global (L2-local after XCD remap),
            // reused by both m chains.
            bf16x8 vf[2][4];
#pragma unroll
            for (int ni = 0; ni < 4; ++ni) {
                const ushort_t* vp = vBase + (size_t)(ni * 16) * Ss + kt * 128 + sub * 64;
                vf[0][ni] = *(const bf16x8*)(vp);        // keys c=0
                vf[1][ni] = *(const bf16x8*)(vp + 32);   // keys c=1
            }

            // S = Q K^T on Ks[cur], subtile rows sub*64..
            f32x4 sAcc[2][4] = {};
            __builtin_amdgcn_s_setprio(1);
#pragma unroll
            for (int ni = 0; ni < 4; ++ni) {
                bf16x8 b0 = *(const bf16x8*)&Ks[cur][(sub * 64 + ni * 16 + l15) * 64 + ((quad * 8) ^ swq)];
                bf16x8 b1 = *(const bf16x8*)&Ks[cur][(sub * 64 + ni * 16 + l15) * 64 + (((quad + 4) * 8) ^ swq)];
#pragma unroll
                for (int m = 0; m < 2; ++m) {
                    sAcc[m][ni] = __builtin_amdgcn_mfma_f32_16x16x32_bf16(aQ[m][0], b0, sAcc[m][ni], 0, 0, 0);
                    sAcc[m][ni] = __builtin_amdgcn_mfma_f32_16x16x32_bf16(aQ[m][1], b1, sAcc[m][ni], 0, 0, 0);
                }
            }
            __builtin_amdgcn_s_setprio(0);

            // softmax (per-wave; P round-trips through Ps[w], lgkmcnt-ordered)
#pragma unroll
            for (int m = 0; m < 2; ++m)
#pragma unroll
                for (int ni = 0; ni < 4; ++ni)
#pragma unroll
                    for (int r = 0; r < 4; ++r) {
                        float p = fast_exp2(sAcc[m][ni][r] * scl2);
                        lsum[m][r] += p;
                        Ps[w][(m * 16 + quad * 4 + r) * 68 + ni * 16 + l15] = f2bf_hi(p);
                    }

            // O += P V   (V in registers, shared across m; no barrier needed)
            __builtin_amdgcn_s_setprio(1);
#pragma unroll
            for (int c = 0; c < 2; ++c) {
                bf16x8 aP0 = *(const bf16x8*)&Ps[w][l15 * 68 + c * 32 + quad * 8];
                bf16x8 aP1 = *(const bf16x8*)&Ps[w][(16 + l15) * 68 + c * 32 + quad * 8];
#pragma unroll
                for (int ni = 0; ni < 4; ++ni) {
                    accO[0][ni] = __builtin_amdgcn_mfma_f32_16x16x32_bf16(aP0, vf[c][ni], accO[0][ni], 0, 0, 0);
                    accO[1][ni] = __builtin_amdgcn_mfma_f32_16x16x32_bf16(aP1, vf[c][ni], accO[1][ni], 0, 0, 0);
                }
            }
            __builtin_amdgcn_s_setprio(0);
        }
    }

#pragma unroll
    for (int m = 0; m < 2; ++m)
#pragma unroll
        for (int r = 0; r < 4; ++r) {
            lsum[m][r] += __shfl_xor(lsum[m][r], 1);
            lsum[m][r] += __shfl_xor(lsum[m][r], 2);
            lsum[m][r] += __shfl_xor(lsum[m][r], 4);
            lsum[m][r] += __shfl_xor(lsum[m][r], 8);
        }

#pragma unroll
    for (int m = 0; m < 2; ++m)
#pragma unroll
        for (int r = 0; r < 4; ++r) {
            int srow = qt * 128 + w * 32 + m * 16 + quad * 4 + r;
            float inv = 1.f / lsum[m][r];
#pragma unroll
            for (int ni = 0; ni < 4; ++ni) {
                int d = ni * 16 + l15;
                ctx[((size_t)(b_ * Ss + srow)) * Ed + h * Dd + d] = f2bf_hi(accO[m][ni][r] * inv);
            }
        }
}

extern "C" void kernel_launch(void* const* d_in, const int* in_sizes, int n_in,
                              void* d_out, int out_size, void* d_ws, size_t ws_size,
                              hipStream_t stream) {
    const float* x  = (const float*)d_in[0];
    const float* Wq = (const float*)d_in[1];
    const float* bq = (const float*)d_in[2];
    const float* Wk = (const float*)d_in[3];
    const float* bk = (const float*)d_in[4];
    const float* Wv = (const float*)d_in[5];
    const float* bv = (const float*)d_in[6];
    const float* Wo = (const float*)d_in[7];
    const float* bo = (const float*)d_in[8];
    const float* z  = (const float*)d_in[9];
    float* out = (float*)d_out;

    ushort_t* xb  = (ushort_t*)d_ws;              // [M,E]     8 MB
    ushort_t* Wqb = xb  + (size_t)Mm * Ed;        // [E,E]     2 MB
    ushort_t* Wkb = Wqb + (size_t)Ed * Ed;
    ushort_t* Wvb = Wkb + (size_t)Ed * Ed;
    ushort_t* Wob = Wvb + (size_t)Ed * Ed;
    ushort_t* qw  = Wob + (size_t)Ed * Ed;        // [B,H,S,D] 8 MB
    ushort_t* kw  = qw + (size_t)Mm * Ed;         // [B,H,S,D] 8 MB
    ushort_t* vT  = kw + (size_t)Mm * Ed;         // [B,H,D,S] 8 MB
    ushort_t* cx  = vT + (size_t)Mm * Ed;         // [B,S,E]   8 MB

    dim3 blk(256);
    cvt_all<<<dim3((NX4 + 4 * NW4) / 256), blk, 0, stream>>>(
        x, Wq, Wk, Wv, Wo, xb, Wqb, Wkb, Wvb, Wob);
    qkv_gemm<<<dim3(Mm / 128, Ed / 128, 3), blk, 0, stream>>>(
        xb, Wqb, bq, Wkb, bk, Wvb, bv, qw, kw, vT);
    attn<<<dim3(Ss / 128, 2 * Hh), blk, 0, stream>>>(qw, kw, vT, z, cx);
    out_gemm<<<dim3(Mm / 128, Ed / 64), blk, 0, stream>>>(cx, Wob, bo, z, out);
}